// Round 5
// baseline (61.782 us; speedup 1.0000x reference)
//
#include <hip/hip_runtime.h>

// KernelExpansion: out[m] = sum_n sigma^2 * w[n] * exp(-0.5*||s_n - x_m||^2 / l^2)
// Round-5: MFMA path, latency-tuned.
//  - prep_s pre-scales s by m2c2 = log2e/l^2 before bf16 hi/lo split, so the
//    MFMA acc IS the exp2 argument (no per-element mul in the epilogue).
//  - prep_x eliminated: each wave builds its x B-fragments + ||x||^2 partials
//    in-register from fp32 (q==3 lanes are the K-pad, all zero).
//  - MFMA chains acc0/acc1 interleaved (dep distance 2); p kept as f32x4
//    (4 independent fma chains); #pragma unroll 2 for cross-tile ILP.
// C/D layout (verified by round-4 pass): acc[i] -> n-row q*4+i, m-col r.

#define LOG2E_F 1.4426950408889634f

typedef __attribute__((ext_vector_type(8))) short bf16x8;   // 8 bf16 = 4 VGPRs
typedef __attribute__((ext_vector_type(4))) float f32x4;
typedef float v2f_ __attribute__((ext_vector_type(2)));

constexpr int D      = 24;
constexpr int KP     = 32;   // padded K (cols 24..31 zero)
constexpr int NSPLIT = 16;   // n-chunks; waves = (M/32)*NSPLIT = 8192 = capacity
constexpr int TPB    = 256;

__device__ inline unsigned short f32_to_bf16_rne(float f) {
    unsigned u = __builtin_bit_cast(unsigned, f);
    u += 0x7fffu + ((u >> 16) & 1u);
    return (unsigned short)(u >> 16);
}
__device__ inline float bf16_to_f32(unsigned short h) {
    unsigned u = ((unsigned)h) << 16;
    return __builtin_bit_cast(float, u);
}

// ---- setup: samples -> (m2c2*s) hi/lo bf16 [N][32]; w'[n] = sg^2 w_n 2^{c2||s||^2}
__global__ void prep_s(const float* __restrict__ s, const float* __restrict__ weights,
                       const float* __restrict__ sigma_p, const float* __restrict__ length_p,
                       unsigned short* __restrict__ shi, unsigned short* __restrict__ slo,
                       float* __restrict__ wp, int N) {
    int n = blockIdx.x * blockDim.x + threadIdx.x;
    if (n >= N) return;
    float l    = length_p[0];
    float sg   = sigma_p[0];
    float c2   = -0.5f * LOG2E_F / (l * l);
    float m2c2 = -2.f * c2;               // log2e / l^2
    const float* sr = s + (size_t)n * D;
    unsigned short hi[KP], lo[KP];
    float ssq = 0.f;
#pragma unroll
    for (int d = 0; d < D; ++d) {
        float v = sr[d];
        ssq = fmaf(v, v, ssq);
        float vs = m2c2 * v;              // pre-scale so acc = exp2 argument
        unsigned short h = f32_to_bf16_rne(vs);
        hi[d] = h;
        lo[d] = f32_to_bf16_rne(vs - bf16_to_f32(h));
    }
#pragma unroll
    for (int d = D; d < KP; ++d) { hi[d] = 0; lo[d] = 0; }
#pragma unroll
    for (int q = 0; q < KP / 8; ++q) {
        bf16x8 vh, vl;
#pragma unroll
        for (int j = 0; j < 8; ++j) { vh[j] = (short)hi[q * 8 + j]; vl[j] = (short)lo[q * 8 + j]; }
        *reinterpret_cast<bf16x8*>(shi + (size_t)n * KP + q * 8) = vh;
        *reinterpret_cast<bf16x8*>(slo + (size_t)n * KP + q * 8) = vl;
    }
    wp[n] = sg * sg * weights[n] * __builtin_amdgcn_exp2f(c2 * ssq);
}

// ---- main: each wave owns 2 column-tiles (32 m) x one n-chunk
__global__ __launch_bounds__(TPB) void ke_mfma(
    const float* __restrict__ x,
    const unsigned short* __restrict__ shi, const unsigned short* __restrict__ slo,
    const float* __restrict__ wp, const float* __restrict__ length_p,
    float* __restrict__ out, int M, int N) {
    int lane = threadIdx.x & 63;
    int wave = blockIdx.x * (TPB / 64) + (threadIdx.x >> 6);
    int MG   = M / 32;
    int ns   = wave / MG;                 // block's 4 waves share ns (MG%4==0)
    int mg   = wave - ns * MG;
    int m0   = mg * 32;
    int r    = lane & 15;
    int q    = lane >> 4;

    float l  = length_p[0];
    float c2 = -0.5f * LOG2E_F / (l * l);

    // Build x B-fragments in-register. Lane (r,q) holds row elements
    // [q*8, q*8+8) of rows m0+r (tile 0) and m0+16+r (tile 1); q==3 is K-pad.
    float xv0[8], xv1[8];
    if (q < 3) {
        const float4* xp0 = reinterpret_cast<const float4*>(x + (size_t)(m0 + r) * D + q * 8);
        const float4* xp1 = reinterpret_cast<const float4*>(x + (size_t)(m0 + 16 + r) * D + q * 8);
        float4 a0 = xp0[0], a1 = xp0[1];
        float4 b0 = xp1[0], b1 = xp1[1];
        xv0[0]=a0.x; xv0[1]=a0.y; xv0[2]=a0.z; xv0[3]=a0.w;
        xv0[4]=a1.x; xv0[5]=a1.y; xv0[6]=a1.z; xv0[7]=a1.w;
        xv1[0]=b0.x; xv1[1]=b0.y; xv1[2]=b0.z; xv1[3]=b0.w;
        xv1[4]=b1.x; xv1[5]=b1.y; xv1[6]=b1.z; xv1[7]=b1.w;
    } else {
#pragma unroll
        for (int j = 0; j < 8; ++j) { xv0[j] = 0.f; xv1[j] = 0.f; }
    }
    float xsq0 = 0.f, xsq1 = 0.f;
    bf16x8 b0h, b0l, b1h, b1l;
#pragma unroll
    for (int j = 0; j < 8; ++j) {
        xsq0 = fmaf(xv0[j], xv0[j], xsq0);
        xsq1 = fmaf(xv1[j], xv1[j], xsq1);
        unsigned short h0 = f32_to_bf16_rne(xv0[j]);
        unsigned short h1 = f32_to_bf16_rne(xv1[j]);
        b0h[j] = (short)h0; b0l[j] = (short)f32_to_bf16_rne(xv0[j] - bf16_to_f32(h0));
        b1h[j] = (short)h1; b1l[j] = (short)f32_to_bf16_rne(xv1[j] - bf16_to_f32(h1));
    }
    asm("" : "+v"(b0h), "+v"(b0l), "+v"(b1h), "+v"(b1l));

    int ntiles = N / 16;
    int per    = ntiles / NSPLIT;
    int t0     = ns * per;

    f32x4 p0v = {0.f, 0.f, 0.f, 0.f};
    f32x4 p1v = {0.f, 0.f, 0.f, 0.f};
#pragma unroll 2
    for (int t = t0; t < t0 + per; ++t) {
        int n0 = t * 16;
        size_t so = ((size_t)(n0 + r)) * KP + q * 8;
        bf16x8 ah = *reinterpret_cast<const bf16x8*>(shi + so);
        bf16x8 al = *reinterpret_cast<const bf16x8*>(slo + so);
        f32x4 wq = *reinterpret_cast<const f32x4*>(wp + n0 + q * 4);

        f32x4 acc0 = {0.f, 0.f, 0.f, 0.f};
        f32x4 acc1 = {0.f, 0.f, 0.f, 0.f};
        // two chains interleaved: dep distance 2 per acc
        acc0 = __builtin_amdgcn_mfma_f32_16x16x32_bf16(ah, b0h, acc0, 0, 0, 0);
        acc1 = __builtin_amdgcn_mfma_f32_16x16x32_bf16(ah, b1h, acc1, 0, 0, 0);
        acc0 = __builtin_amdgcn_mfma_f32_16x16x32_bf16(al, b0h, acc0, 0, 0, 0);
        acc1 = __builtin_amdgcn_mfma_f32_16x16x32_bf16(al, b1h, acc1, 0, 0, 0);
        acc0 = __builtin_amdgcn_mfma_f32_16x16x32_bf16(ah, b0l, acc0, 0, 0, 0);
        acc1 = __builtin_amdgcn_mfma_f32_16x16x32_bf16(ah, b1l, acc1, 0, 0, 0);
#pragma unroll
        for (int i = 0; i < 4; ++i) {
            p0v[i] = fmaf(wq[i], __builtin_amdgcn_exp2f(acc0[i]), p0v[i]);
            p1v[i] = fmaf(wq[i], __builtin_amdgcn_exp2f(acc1[i]), p1v[i]);
        }
    }
    float p0 = (p0v[0] + p0v[1]) + (p0v[2] + p0v[3]);
    float p1 = (p1v[0] + p1v[1]) + (p1v[2] + p1v[3]);
    // reduce over the 4 q-quarters (columns r fixed): sums p and ||x||^2
    p0   += __shfl_xor(p0, 16, 64);
    p0   += __shfl_xor(p0, 32, 64);
    p1   += __shfl_xor(p1, 16, 64);
    p1   += __shfl_xor(p1, 32, 64);
    xsq0 += __shfl_xor(xsq0, 16, 64);
    xsq0 += __shfl_xor(xsq0, 32, 64);
    xsq1 += __shfl_xor(xsq1, 16, 64);
    xsq1 += __shfl_xor(xsq1, 32, 64);
    if (lane < 16) {
        atomicAdd(&out[m0 + r],      p0 * __builtin_amdgcn_exp2f(c2 * xsq0));
        atomicAdd(&out[m0 + 16 + r], p1 * __builtin_amdgcn_exp2f(c2 * xsq1));
    }
}

// ---- fallback: fp32 VALU kernel (no workspace needed)
constexpr int MPT  = 2;
constexpr int MBLK = TPB * MPT;

__global__ __launch_bounds__(TPB) void ke_plain(
    const float* __restrict__ x, const float* __restrict__ samples,
    const float* __restrict__ weights, const float* __restrict__ sigma_p,
    const float* __restrict__ length_p, float* __restrict__ out,
    int M, int N, int nsplit, int chunk) {
    int mb = blockIdx.x / nsplit;
    int ns = blockIdx.x - mb * nsplit;
    int t  = threadIdx.x;
    int m0 = mb * MBLK + t;
    int m1 = m0 + TPB;
    int m0c = (m0 < M) ? m0 : 0;
    int m1c = (m1 < M) ? m1 : 0;

    v2f_ xaq[D / 2], xbq[D / 2];
    const v2f_* xp0 = reinterpret_cast<const v2f_*>(x + (size_t)m0c * D);
    const v2f_* xp1 = reinterpret_cast<const v2f_*>(x + (size_t)m1c * D);
#pragma unroll
    for (int qq = 0; qq < D / 2; ++qq) { xaq[qq] = xp0[qq]; xbq[qq] = xp1[qq]; }
#pragma unroll
    for (int qq = 0; qq < D / 2; ++qq) { asm("" : "+v"(xaq[qq])); asm("" : "+v"(xbq[qq])); }

    float l   = length_p[0];
    float c   = -0.5f * LOG2E_F / (l * l);
    float m2c = -2.f * c;
    float sg  = sigma_p[0];
    float sg2 = sg * sg;

    v2f_ qa = {0.f, 0.f}, qb = {0.f, 0.f};
#pragma unroll
    for (int qq = 0; qq < D / 2; ++qq) {
        qa = __builtin_elementwise_fma(xaq[qq], xaq[qq], qa);
        qb = __builtin_elementwise_fma(xbq[qq], xbq[qq], qb);
    }
    float cxa = c * (qa.x + qa.y);
    float cxb = c * (qb.x + qb.y);

    float acc0 = 0.f, acc1 = 0.f;
    int n0 = ns * chunk;
    int n1 = n0 + chunk;
    if (n1 > N) n1 = N;
#pragma unroll 2
    for (int n = n0; n < n1; ++n) {
        const v2f_* s2 = reinterpret_cast<const v2f_*>(samples + (size_t)n * D);
        v2f_ da = {0.f, 0.f}, db = {0.f, 0.f}, sq = {0.f, 0.f};
#pragma unroll
        for (int qq = 0; qq < D / 2; ++qq) {
            v2f_ sv = s2[qq];
            sq = __builtin_elementwise_fma(sv, sv, sq);
            da = __builtin_elementwise_fma(sv, xaq[qq], da);
            db = __builtin_elementwise_fma(sv, xbq[qq], db);
        }
        float cn = c * (sq.x + sq.y);
        float wn = sg2 * weights[n];
        float e0 = fmaf(m2c, da.x + da.y, cn);
        float e1 = fmaf(m2c, db.x + db.y, cn);
        acc0 = fmaf(wn, __builtin_amdgcn_exp2f(e0), acc0);
        acc1 = fmaf(wn, __builtin_amdgcn_exp2f(e1), acc1);
    }
    if (m0 < M) atomicAdd(&out[m0], acc0 * __builtin_amdgcn_exp2f(cxa));
    if (m1 < M) atomicAdd(&out[m1], acc1 * __builtin_amdgcn_exp2f(cxb));
}

extern "C" void kernel_launch(void* const* d_in, const int* in_sizes, int n_in,
                              void* d_out, int out_size, void* d_ws, size_t ws_size,
                              hipStream_t stream) {
    const float* x       = (const float*)d_in[0];
    const float* samples = (const float*)d_in[1];
    const float* weights = (const float*)d_in[2];
    const float* sigma_p = (const float*)d_in[3];
    const float* length_p= (const float*)d_in[4];
    float* out = (float*)d_out;

    int M = in_sizes[0] / D;
    int N = in_sizes[1] / D;

    hipMemsetAsync(out, 0, (size_t)out_size * sizeof(float), stream);

    // workspace layout (bytes)
    size_t shi_off = 0;
    size_t slo_off = shi_off + (size_t)N * KP * 2;
    size_t wp_off  = slo_off + (size_t)N * KP * 2;
    size_t need    = wp_off + (size_t)N * 4;

    bool mfma_ok = ws_size >= need && (M % 32) == 0 && ((M / 32) % (TPB / 64)) == 0 &&
                   (N % 16) == 0 && ((N / 16) % NSPLIT) == 0;

    if (mfma_ok) {
        char* ws = (char*)d_ws;
        unsigned short* shi = (unsigned short*)(ws + shi_off);
        unsigned short* slo = (unsigned short*)(ws + slo_off);
        float* wp = (float*)(ws + wp_off);

        prep_s<<<dim3((N + TPB - 1) / TPB), dim3(TPB), 0, stream>>>(
            samples, weights, sigma_p, length_p, shi, slo, wp, N);

        int waves  = (M / 32) * NSPLIT;           // 8192
        int blocks = waves / (TPB / 64);          // 2048
        ke_mfma<<<dim3(blocks), dim3(TPB), 0, stream>>>(
            x, shi, slo, wp, length_p, out, M, N);
    } else {
        int mbcnt  = (M + MBLK - 1) / MBLK;
        int nsplit = 2048 / (mbcnt > 0 ? mbcnt : 1);
        if (nsplit < 1) nsplit = 1;
        if (nsplit > N) nsplit = N;
        int chunk = (N + nsplit - 1) / nsplit;
        ke_plain<<<dim3(mbcnt * nsplit), dim3(TPB), 0, stream>>>(
            x, samples, weights, sigma_p, length_p, out, M, N, nsplit, chunk);
    }
}

// Round 6
// 51.528 us; speedup vs baseline: 1.1990x; 1.1990x over previous
//
#include <hip/hip_runtime.h>

// KernelExpansion: out[m] = sum_n sigma^2 * w[n] * exp(-0.5*||s_n - x_m||^2 / l^2)
// Round-6: MFMA path, arithmetic-intensity fix.
//  Diagnosis r4/r5: ~4000 cyc/iter critical path = L1 thrash (67KB/CU/iter
//  streamed vs 32KB L1); only 6 MFMA + ~160 VALU cyc per 2.1KB loaded.
//  Fix: 4 column-tiles per wave (64 m) -> same ah/al/wq loads feed 2x the
//  MFMA/exp2 work; total load traffic halves; MFMA dep distance 4.
//  Reverted r5 regressions: prep_x restored (preformed bf16 frags, no
//  divergent prologue), no unroll pragma, scalar p per tile.
//  Kept r5 win: prep_s pre-scales s by log2e/l^2 so acc == exp2 argument.
// C/D layout (verified r4 pass): acc[i] -> n-row q*4+i, m-col r.

#define LOG2E_F 1.4426950408889634f

typedef __attribute__((ext_vector_type(8))) short bf16x8;   // 8 bf16 = 4 VGPRs
typedef __attribute__((ext_vector_type(4))) float f32x4;
typedef float v2f_ __attribute__((ext_vector_type(2)));

constexpr int D      = 24;
constexpr int KP     = 32;   // padded K (cols 24..31 zero)
constexpr int TILES  = 4;    // 16-col tiles per wave -> 64 m per wave
constexpr int NSPLIT = 32;   // n-chunks; waves = (M/64)*NSPLIT = 8192 = capacity
constexpr int TPB    = 256;

__device__ inline unsigned short f32_to_bf16_rne(float f) {
    unsigned u = __builtin_bit_cast(unsigned, f);
    u += 0x7fffu + ((u >> 16) & 1u);
    return (unsigned short)(u >> 16);
}
__device__ inline float bf16_to_f32(unsigned short h) {
    unsigned u = ((unsigned)h) << 16;
    return __builtin_bit_cast(float, u);
}

// ---- setup: x -> (x_hi, x_lo bf16 [M][32]), cx[m] = c2*||x||^2 (log2 units)
__global__ void prep_x(const float* __restrict__ x, const float* __restrict__ length_p,
                       unsigned short* __restrict__ xhi, unsigned short* __restrict__ xlo,
                       float* __restrict__ cx, int M) {
    int m = blockIdx.x * blockDim.x + threadIdx.x;
    if (m >= M) return;
    float l  = length_p[0];
    float c2 = -0.5f * LOG2E_F / (l * l);
    const float* xr = x + (size_t)m * D;
    unsigned short hi[KP], lo[KP];
    float ssq = 0.f;
#pragma unroll
    for (int d = 0; d < D; ++d) {
        float v = xr[d];
        ssq = fmaf(v, v, ssq);
        unsigned short h = f32_to_bf16_rne(v);
        hi[d] = h;
        lo[d] = f32_to_bf16_rne(v - bf16_to_f32(h));
    }
#pragma unroll
    for (int d = D; d < KP; ++d) { hi[d] = 0; lo[d] = 0; }
#pragma unroll
    for (int q = 0; q < KP / 8; ++q) {
        bf16x8 vh, vl;
#pragma unroll
        for (int j = 0; j < 8; ++j) { vh[j] = (short)hi[q * 8 + j]; vl[j] = (short)lo[q * 8 + j]; }
        *reinterpret_cast<bf16x8*>(xhi + (size_t)m * KP + q * 8) = vh;
        *reinterpret_cast<bf16x8*>(xlo + (size_t)m * KP + q * 8) = vl;
    }
    cx[m] = c2 * ssq;
}

// ---- setup: samples -> (m2c2*s) hi/lo bf16 [N][32]; w'[n] = sg^2 w_n 2^{c2||s||^2}
__global__ void prep_s(const float* __restrict__ s, const float* __restrict__ weights,
                       const float* __restrict__ sigma_p, const float* __restrict__ length_p,
                       unsigned short* __restrict__ shi, unsigned short* __restrict__ slo,
                       float* __restrict__ wp, int N) {
    int n = blockIdx.x * blockDim.x + threadIdx.x;
    if (n >= N) return;
    float l    = length_p[0];
    float sg   = sigma_p[0];
    float c2   = -0.5f * LOG2E_F / (l * l);
    float m2c2 = -2.f * c2;               // log2e / l^2
    const float* sr = s + (size_t)n * D;
    unsigned short hi[KP], lo[KP];
    float ssq = 0.f;
#pragma unroll
    for (int d = 0; d < D; ++d) {
        float v = sr[d];
        ssq = fmaf(v, v, ssq);
        float vs = m2c2 * v;              // pre-scale so acc = exp2 argument
        unsigned short h = f32_to_bf16_rne(vs);
        hi[d] = h;
        lo[d] = f32_to_bf16_rne(vs - bf16_to_f32(h));
    }
#pragma unroll
    for (int d = D; d < KP; ++d) { hi[d] = 0; lo[d] = 0; }
#pragma unroll
    for (int q = 0; q < KP / 8; ++q) {
        bf16x8 vh, vl;
#pragma unroll
        for (int j = 0; j < 8; ++j) { vh[j] = (short)hi[q * 8 + j]; vl[j] = (short)lo[q * 8 + j]; }
        *reinterpret_cast<bf16x8*>(shi + (size_t)n * KP + q * 8) = vh;
        *reinterpret_cast<bf16x8*>(slo + (size_t)n * KP + q * 8) = vl;
    }
    wp[n] = sg * sg * weights[n] * __builtin_amdgcn_exp2f(c2 * ssq);
}

// ---- main: each wave owns 4 column-tiles (64 m) x one n-chunk.
// Block's 4 waves share ns (MG % 4 == 0) -> identical ah/al/wq streams, L1 reuse.
__global__ __launch_bounds__(TPB) void ke_mfma(
    const unsigned short* __restrict__ xhi, const unsigned short* __restrict__ xlo,
    const unsigned short* __restrict__ shi, const unsigned short* __restrict__ slo,
    const float* __restrict__ wp, const float* __restrict__ cx,
    float* __restrict__ out, int M, int N) {
    int lane = threadIdx.x & 63;
    int wave = blockIdx.x * (TPB / 64) + (threadIdx.x >> 6);
    int MG   = M / (TILES * 16);          // column-groups of 64
    int ns   = wave / MG;
    int mg   = wave - ns * MG;
    int m0   = mg * (TILES * 16);
    int r    = lane & 15;
    int q    = lane >> 4;

    // B fragments (x) for 4 column-tiles, pinned for the whole n-loop.
    bf16x8 bh[TILES], bl[TILES];
#pragma unroll
    for (int j = 0; j < TILES; ++j) {
        size_t xo = ((size_t)(m0 + j * 16 + r)) * KP + q * 8;
        bh[j] = *reinterpret_cast<const bf16x8*>(xhi + xo);
        bl[j] = *reinterpret_cast<const bf16x8*>(xlo + xo);
    }
#pragma unroll
    for (int j = 0; j < TILES; ++j) {
        asm("" : "+v"(bh[j]));
        asm("" : "+v"(bl[j]));
    }

    int per = (N / 16) / NSPLIT;          // 16
    int t0  = ns * per;

    float p[TILES] = {0.f, 0.f, 0.f, 0.f};
    for (int t = t0; t < t0 + per; ++t) {
        int n0 = t * 16;
        size_t so = ((size_t)(n0 + r)) * KP + q * 8;
        bf16x8 ah = *reinterpret_cast<const bf16x8*>(shi + so);
        bf16x8 al = *reinterpret_cast<const bf16x8*>(slo + so);
        f32x4 wq = *reinterpret_cast<const f32x4*>(wp + n0 + q * 4);

        f32x4 acc[TILES];
#pragma unroll
        for (int j = 0; j < TILES; ++j) {
            f32x4 z = {0.f, 0.f, 0.f, 0.f};
            acc[j] = __builtin_amdgcn_mfma_f32_16x16x32_bf16(ah, bh[j], z, 0, 0, 0);
        }
#pragma unroll
        for (int j = 0; j < TILES; ++j)
            acc[j] = __builtin_amdgcn_mfma_f32_16x16x32_bf16(al, bh[j], acc[j], 0, 0, 0);
#pragma unroll
        for (int j = 0; j < TILES; ++j)
            acc[j] = __builtin_amdgcn_mfma_f32_16x16x32_bf16(ah, bl[j], acc[j], 0, 0, 0);
#pragma unroll
        for (int j = 0; j < TILES; ++j) {
            float pj = p[j];
            pj = fmaf(wq[0], __builtin_amdgcn_exp2f(acc[j][0]), pj);
            pj = fmaf(wq[1], __builtin_amdgcn_exp2f(acc[j][1]), pj);
            pj = fmaf(wq[2], __builtin_amdgcn_exp2f(acc[j][2]), pj);
            pj = fmaf(wq[3], __builtin_amdgcn_exp2f(acc[j][3]), pj);
            p[j] = pj;
        }
    }
    // reduce over the 4 q-quarters (column r fixed)
#pragma unroll
    for (int j = 0; j < TILES; ++j) {
        p[j] += __shfl_xor(p[j], 16, 64);
        p[j] += __shfl_xor(p[j], 32, 64);
    }
    if (lane < 16) {
#pragma unroll
        for (int j = 0; j < TILES; ++j) {
            int m = m0 + j * 16 + r;
            atomicAdd(&out[m], p[j] * __builtin_amdgcn_exp2f(cx[m]));
        }
    }
}

// ---- fallback: fp32 VALU kernel (no workspace needed)
constexpr int MPT  = 2;
constexpr int MBLK = TPB * MPT;

__global__ __launch_bounds__(TPB) void ke_plain(
    const float* __restrict__ x, const float* __restrict__ samples,
    const float* __restrict__ weights, const float* __restrict__ sigma_p,
    const float* __restrict__ length_p, float* __restrict__ out,
    int M, int N, int nsplit, int chunk) {
    int mb = blockIdx.x / nsplit;
    int ns = blockIdx.x - mb * nsplit;
    int t  = threadIdx.x;
    int m0 = mb * MBLK + t;
    int m1 = m0 + TPB;
    int m0c = (m0 < M) ? m0 : 0;
    int m1c = (m1 < M) ? m1 : 0;

    v2f_ xaq[D / 2], xbq[D / 2];
    const v2f_* xp0 = reinterpret_cast<const v2f_*>(x + (size_t)m0c * D);
    const v2f_* xp1 = reinterpret_cast<const v2f_*>(x + (size_t)m1c * D);
#pragma unroll
    for (int qq = 0; qq < D / 2; ++qq) { xaq[qq] = xp0[qq]; xbq[qq] = xp1[qq]; }
#pragma unroll
    for (int qq = 0; qq < D / 2; ++qq) { asm("" : "+v"(xaq[qq])); asm("" : "+v"(xbq[qq])); }

    float l   = length_p[0];
    float c   = -0.5f * LOG2E_F / (l * l);
    float m2c = -2.f * c;
    float sg  = sigma_p[0];
    float sg2 = sg * sg;

    v2f_ qa = {0.f, 0.f}, qb = {0.f, 0.f};
#pragma unroll
    for (int qq = 0; qq < D / 2; ++qq) {
        qa = __builtin_elementwise_fma(xaq[qq], xaq[qq], qa);
        qb = __builtin_elementwise_fma(xbq[qq], xbq[qq], qb);
    }
    float cxa = c * (qa.x + qa.y);
    float cxb = c * (qb.x + qb.y);

    float acc0 = 0.f, acc1 = 0.f;
    int n0 = ns * chunk;
    int n1 = n0 + chunk;
    if (n1 > N) n1 = N;
#pragma unroll 2
    for (int n = n0; n < n1; ++n) {
        const v2f_* s2 = reinterpret_cast<const v2f_*>(samples + (size_t)n * D);
        v2f_ da = {0.f, 0.f}, db = {0.f, 0.f}, sq = {0.f, 0.f};
#pragma unroll
        for (int qq = 0; qq < D / 2; ++qq) {
            v2f_ sv = s2[qq];
            sq = __builtin_elementwise_fma(sv, sv, sq);
            da = __builtin_elementwise_fma(sv, xaq[qq], da);
            db = __builtin_elementwise_fma(sv, xbq[qq], db);
        }
        float cn = c * (sq.x + sq.y);
        float wn = sg2 * weights[n];
        float e0 = fmaf(m2c, da.x + da.y, cn);
        float e1 = fmaf(m2c, db.x + db.y, cn);
        acc0 = fmaf(wn, __builtin_amdgcn_exp2f(e0), acc0);
        acc1 = fmaf(wn, __builtin_amdgcn_exp2f(e1), acc1);
    }
    if (m0 < M) atomicAdd(&out[m0], acc0 * __builtin_amdgcn_exp2f(cxa));
    if (m1 < M) atomicAdd(&out[m1], acc1 * __builtin_amdgcn_exp2f(cxb));
}

extern "C" void kernel_launch(void* const* d_in, const int* in_sizes, int n_in,
                              void* d_out, int out_size, void* d_ws, size_t ws_size,
                              hipStream_t stream) {
    const float* x       = (const float*)d_in[0];
    const float* samples = (const float*)d_in[1];
    const float* weights = (const float*)d_in[2];
    const float* sigma_p = (const float*)d_in[3];
    const float* length_p= (const float*)d_in[4];
    float* out = (float*)d_out;

    int M = in_sizes[0] / D;
    int N = in_sizes[1] / D;

    hipMemsetAsync(out, 0, (size_t)out_size * sizeof(float), stream);

    // workspace layout (bytes)
    size_t xhi_off = 0;
    size_t xlo_off = xhi_off + (size_t)M * KP * 2;
    size_t shi_off = xlo_off + (size_t)M * KP * 2;
    size_t slo_off = shi_off + (size_t)N * KP * 2;
    size_t wp_off  = slo_off + (size_t)N * KP * 2;
    size_t cx_off  = wp_off + (size_t)N * 4;
    size_t need    = cx_off + (size_t)M * 4;

    int  MT = TILES * 16;  // 64 m per wave
    bool mfma_ok = ws_size >= need &&
                   (M % MT) == 0 && ((M / MT) % (TPB / 64)) == 0 &&
                   (N % 16) == 0 && ((N / 16) % NSPLIT) == 0;

    if (mfma_ok) {
        char* ws = (char*)d_ws;
        unsigned short* xhi = (unsigned short*)(ws + xhi_off);
        unsigned short* xlo = (unsigned short*)(ws + xlo_off);
        unsigned short* shi = (unsigned short*)(ws + shi_off);
        unsigned short* slo = (unsigned short*)(ws + slo_off);
        float* wp = (float*)(ws + wp_off);
        float* cx = (float*)(ws + cx_off);

        prep_x<<<dim3((M + TPB - 1) / TPB), dim3(TPB), 0, stream>>>(
            x, length_p, xhi, xlo, cx, M);
        prep_s<<<dim3((N + TPB - 1) / TPB), dim3(TPB), 0, stream>>>(
            samples, weights, sigma_p, length_p, shi, slo, wp, N);

        int waves  = (M / MT) * NSPLIT;           // 8192
        int blocks = waves / (TPB / 64);          // 2048
        ke_mfma<<<dim3(blocks), dim3(TPB), 0, stream>>>(
            xhi, xlo, shi, slo, wp, cx, out, M, N);
    } else {
        int mbcnt  = (M + MBLK - 1) / MBLK;
        int nsplit = 2048 / (mbcnt > 0 ? mbcnt : 1);
        if (nsplit < 1) nsplit = 1;
        if (nsplit > N) nsplit = N;
        int chunk = (N + nsplit - 1) / nsplit;
        ke_plain<<<dim3(mbcnt * nsplit), dim3(TPB), 0, stream>>>(
            x, samples, weights, sigma_p, length_p, out, M, N, nsplit, chunk);
    }
}